// Round 1
// baseline (780.190 us; speedup 1.0000x reference)
//
#include <hip/hip_runtime.h>

#define B_    256
#define CIN   128
#define CH    64
#define NPX   1024   // 32*32
#define NWIN  49
#define NEG_INF_F (-1e30f)

// ---------------------------------------------------------------------------
// Transpose W (Ch x Cin -> Cin x Ch) so the conv kernel's weight reads are
// uniform+consecutive (s_load_dwordx16 friendly). Also resolves same_WqWk on
// device (host cannot read device scalars under graph capture).
// ---------------------------------------------------------------------------
__global__ __launch_bounds__(256) void wtrans_kernel(
    const float* __restrict__ Wq, const float* __restrict__ Wk,
    const int* __restrict__ same_flag,
    float* __restrict__ WtQ, float* __restrict__ WtK)
{
    const float* Wsel = (same_flag[0] != 0) ? Wq : Wk;
    for (int idx = threadIdx.x; idx < CH * CIN; idx += 256) {
        int i = idx >> 6;   // input channel 0..127
        int o = idx & 63;   // output channel 0..63
        WtQ[idx] = Wq[o * CIN + i];
        WtK[idx] = Wsel[o * CIN + i];
    }
}

// ---------------------------------------------------------------------------
// 1x1 conv: dst[b,o,p] = sum_i Wt[i,o] * x[b,i,p] + bias[o]
// grid = B*4 blocks, 256 threads, 1 pixel per thread, acc[64] in VGPRs.
// Wt reads are thread-uniform -> scalar loads, parallel to the VALU FMAs.
// bias = (sel_flag && *sel_flag) ? bias_b : bias_a   (device-side select)
// ---------------------------------------------------------------------------
__global__ __launch_bounds__(256) void conv_kernel(
    const float* __restrict__ x, const float* __restrict__ Wt,
    const float* __restrict__ bias_a, const float* __restrict__ bias_b,
    const int* __restrict__ sel_flag,
    float* __restrict__ dst)
{
    const float* bias = (sel_flag != nullptr && sel_flag[0] != 0) ? bias_b : bias_a;
    int b  = blockIdx.x >> 2;
    int px = ((blockIdx.x & 3) << 8) + threadIdx.x;

    const float* xb = x + (size_t)b * (CIN * NPX) + px;
    float acc[CH];
#pragma unroll
    for (int o = 0; o < CH; ++o) acc[o] = bias[o];

#pragma unroll 4
    for (int i = 0; i < CIN; ++i) {
        float xv = xb[(size_t)i * NPX];
        const float* wrow = Wt + (i << 6);
#pragma unroll
        for (int o = 0; o < CH; ++o) acc[o] = fmaf(wrow[o], xv, acc[o]);
    }

    float* db = dst + (size_t)b * (CH * NPX) + px;
#pragma unroll
    for (int o = 0; o < CH; ++o) db[o << 10] = acc[o];
}

// ---------------------------------------------------------------------------
// Fused local attention for one 8-row tile of one image.
// block = (b, tile of 8 rows x 32 cols), 256 threads, 1 pixel per thread.
// Phase A: scores[49] in regs; K staged in LDS 4-channel-interleaved
//          [14 rows][40 cols][4 ch] so each window tap is one float4 read
//          (16B/lane stride -> conflict-free).
// Phase B: masked softmax in registers (invalid -> -1e30 -> exp == 0).
// Phase C: same staging for V (128 ch in 32 groups of 4), attn in regs.
// ---------------------------------------------------------------------------
__global__ __launch_bounds__(256) void attend_kernel(
    const float* __restrict__ Q, const float* __restrict__ K,
    const float* __restrict__ V,          // key-side raw features, CIN ch
    float* __restrict__ out,              // full output base (B,256,32,32)
    int chan_base,                        // 0 = left half, 128 = right half
    const float* __restrict__ copy_src,   // left features (self_attend==0 path)
    const int* __restrict__ self_flag)
{
    __shared__ __align__(16) float buf[14 * 40 * 4];   // 8960 B

    int b    = blockIdx.x >> 2;
    int tile = blockIdx.x & 3;
    int h0   = tile << 3;
    int r    = threadIdx.x >> 5;   // 0..7
    int w    = threadIdx.x & 31;
    int h    = h0 + r;

    if (copy_src != nullptr && self_flag[0] == 0) {
        // self_attend == 0: left half of output is just left_features
        const float* s = copy_src + (size_t)b * (CIN * NPX) + (h << 5) + w;
        float* d = out + (size_t)b * (2 * CIN * NPX) + (size_t)chan_base * NPX + (h << 5) + w;
        for (int c = 0; c < CIN; ++c) d[c << 10] = s[c << 10];
        return;
    }

    float sc[NWIN];
#pragma unroll
    for (int i = 0; i < NWIN; ++i) sc[i] = 0.f;

    const float* Kb = K + (size_t)b * (CH * NPX);
    const float* Qb = Q + (size_t)b * (CH * NPX);

    // ---- Phase A: scores over 64 Q/K channels, 4 at a time ----
    for (int cg = 0; cg < CH / 4; ++cg) {
        __syncthreads();
        for (int idx = threadIdx.x; idx < 2240; idx += 256) {
            int c   = idx / 560;
            int rem = idx - c * 560;
            int row = rem / 40;
            int col = rem - row * 40;
            int gr  = h0 - 3 + row;     // -3..34
            int gc  = col - 4;          // -4..35
            float v = 0.f;
            if ((unsigned)gr < 32u && (unsigned)gc < 32u)
                v = Kb[((cg * 4 + c) << 10) + (gr << 5) + gc];
            buf[(row * 40 + col) * 4 + c] = v;
        }
        __syncthreads();
        float q0 = Qb[((cg * 4 + 0) << 10) + (h << 5) + w];
        float q1 = Qb[((cg * 4 + 1) << 10) + (h << 5) + w];
        float q2 = Qb[((cg * 4 + 2) << 10) + (h << 5) + w];
        float q3 = Qb[((cg * 4 + 3) << 10) + (h << 5) + w];
        const float4* b4 = (const float4*)buf;
#pragma unroll
        for (int dh = 0; dh < 7; ++dh) {
#pragma unroll
            for (int dw = 0; dw < 7; ++dw) {
                float4 kv = b4[(r + dh) * 40 + (w + dw + 1)];
                float s = sc[dh * 7 + dw];
                s = fmaf(q0, kv.x, s);
                s = fmaf(q1, kv.y, s);
                s = fmaf(q2, kv.z, s);
                s = fmaf(q3, kv.w, s);
                sc[dh * 7 + dw] = s;
            }
        }
    }

    // ---- Phase B: masked softmax (identical semantics to reference) ----
    float m = NEG_INF_F;
#pragma unroll
    for (int dh = 0; dh < 7; ++dh) {
#pragma unroll
        for (int dw = 0; dw < 7; ++dw) {
            int i = dh * 7 + dw;
            bool valid = ((unsigned)(h + dh - 3) < 32u) && ((unsigned)(w + dw - 3) < 32u);
            sc[i] = valid ? sc[i] : NEG_INF_F;
            m = fmaxf(m, sc[i]);
        }
    }
    float sum = 0.f;
#pragma unroll
    for (int i = 0; i < NWIN; ++i) { sc[i] = __expf(sc[i] - m); sum += sc[i]; }
    float inv = 1.f / sum;
#pragma unroll
    for (int i = 0; i < NWIN; ++i) sc[i] *= inv;

    // ---- Phase C: weighted V sum over 128 channels, 4 at a time ----
    const float* Vb = V + (size_t)b * (CIN * NPX);
    float* ob = out + (size_t)b * (2 * CIN * NPX) + (size_t)chan_base * NPX + (h << 5) + w;

    for (int vg = 0; vg < CIN / 4; ++vg) {
        __syncthreads();
        for (int idx = threadIdx.x; idx < 2240; idx += 256) {
            int c   = idx / 560;
            int rem = idx - c * 560;
            int row = rem / 40;
            int col = rem - row * 40;
            int gr  = h0 - 3 + row;
            int gc  = col - 4;
            float v = 0.f;
            if ((unsigned)gr < 32u && (unsigned)gc < 32u)
                v = Vb[((vg * 4 + c) << 10) + (gr << 5) + gc];
            buf[(row * 40 + col) * 4 + c] = v;
        }
        __syncthreads();
        float a0 = 0.f, a1 = 0.f, a2 = 0.f, a3 = 0.f;
        const float4* b4 = (const float4*)buf;
#pragma unroll
        for (int dh = 0; dh < 7; ++dh) {
#pragma unroll
            for (int dw = 0; dw < 7; ++dw) {
                float4 vv = b4[(r + dh) * 40 + (w + dw + 1)];
                float p = sc[dh * 7 + dw];
                a0 = fmaf(p, vv.x, a0);
                a1 = fmaf(p, vv.y, a1);
                a2 = fmaf(p, vv.z, a2);
                a3 = fmaf(p, vv.w, a3);
            }
        }
        ob[(vg * 4 + 0) << 10] = a0;
        ob[(vg * 4 + 1) << 10] = a1;
        ob[(vg * 4 + 2) << 10] = a2;
        ob[(vg * 4 + 3) << 10] = a3;
    }
}

// ---------------------------------------------------------------------------
// Launch:
//   wtrans                    (select Wk/Wq per same_WqWk, transpose)
//   conv  left  -> wsQ        (Q_left, shared by both attends)
//   conv  right -> wsK        (K_right)
//   attend(Q_left, K_right, right) -> out[:,128:256]
//   conv  left  -> wsK        (K_left, reuses the K buffer; stream-ordered)
//   attend(Q_left, K_left,  left ) -> out[:,0:128]  (or copy if !self_attend)
// Workspace: 2 * 64 MiB (Q,K) + 2 * 32 KiB (W transposes) = 128.06 MiB.
// ---------------------------------------------------------------------------
extern "C" void kernel_launch(void* const* d_in, const int* in_sizes, int n_in,
                              void* d_out, int out_size, void* d_ws, size_t ws_size,
                              hipStream_t stream)
{
    (void)in_sizes; (void)n_in; (void)out_size; (void)ws_size;

    const float* left  = (const float*)d_in[0];
    const float* right = (const float*)d_in[1];
    const float* Wq    = (const float*)d_in[2];
    const float* bq    = (const float*)d_in[3];
    const float* Wk    = (const float*)d_in[4];
    const float* bk    = (const float*)d_in[5];
    // d_in[6] = vis_CA (unused by reference)
    const int* self_flag = (const int*)d_in[7];
    const int* same_flag = (const int*)d_in[8];

    float* wsQ = (float*)d_ws;                       // 256*64*1024 floats
    float* wsK = wsQ + (size_t)B_ * CH * NPX;
    float* WtQ = wsK + (size_t)B_ * CH * NPX;        // 8192 floats
    float* WtK = WtQ + CH * CIN;

    float* out = (float*)d_out;

    wtrans_kernel<<<1, 256, 0, stream>>>(Wq, Wk, same_flag, WtQ, WtK);

    // Q from left features (always Wq/bq)
    conv_kernel<<<dim3(B_ * 4), 256, 0, stream>>>(left, WtQ, bq, bq, nullptr, wsQ);

    // K from right features (Wk/bk, or Wq/bq if same_WqWk)
    conv_kernel<<<dim3(B_ * 4), 256, 0, stream>>>(right, WtK, bk, bq, same_flag, wsK);
    attend_kernel<<<dim3(B_ * 4), 256, 0, stream>>>(wsQ, wsK, right, out, CIN, nullptr, self_flag);

    // K from left features; attend-left (or plain copy when self_attend==0)
    conv_kernel<<<dim3(B_ * 4), 256, 0, stream>>>(left, WtK, bk, bq, same_flag, wsK);
    attend_kernel<<<dim3(B_ * 4), 256, 0, stream>>>(wsQ, wsK, left, out, 0, left, self_flag);
}